// Round 4
// 2679.126 us; speedup vs baseline: 1.3970x; 1.3970x over previous
//
#include <hip/hip_runtime.h>

constexpr int MQ   = 131072;
constexpr int NPTS = 1024;

// ---- workspace layout (identical in kind to the round-0 passing kernel) ----
constexpr size_t WS_PTS4 = 4096;   // float4 points at +4096; denom (8 f32) at 0

// ---- np-exact f32 arithmetic: no FMA contraction, np's association order ----
__device__ __forceinline__ float np_sq3(float x, float y, float z){
  #pragma clang fp contract(off)
  float s = (x*x + y*y) + z*z;
  return s;
}
__device__ __forceinline__ float np_d2(float a2, float b2,
                                       float c0, float c1, float c2,
                                       float p0, float p1, float p2){
  #pragma clang fp contract(off)
  float dot = (c0*p0 + c1*p1) + c2*p2;
  float d   = (a2 + b2) - 2.0f*dot;
  return d;
}

// ---------- host-sanity failure marker (f32 output!) ----------
__global__ void k_err_r15(float code, float* __restrict__ out){
  out[0] = code;
}

// ---------- prep: zero denom, pack points {x,y,z,|p|^2 np-exact} ----------
__global__ __launch_bounds__(256) void k_prep_r15(const float* __restrict__ pts,
                                                  float4* __restrict__ pts4,
                                                  float* __restrict__ denom){
  int i = blockIdx.x*256 + threadIdx.x;          // 2048 threads
  if (i < 8) denom[i] = 0.f;
  if (i < 2*NPTS){
    float x = pts[i*3+0], y = pts[i*3+1], z = pts[i*3+2];
    pts4[i] = make_float4(x, y, z, np_sq3(x,y,z));
  }
}

// ---------- pass 1: denom[n][k] = sum_m 1/dist  (exact r11 kernel) ----------
__global__ __launch_bounds__(256) void k_denom_r15(const float* __restrict__ coords,
                                                   const float4* __restrict__ pts4,
                                                   float* __restrict__ denom){
  __shared__ float red[4][4];
  int n = blockIdx.y;
  int m = blockIdx.x*256 + threadIdx.x;
  size_t g = (size_t)n*MQ + m;
  float c0 = coords[g*3+0], c1 = coords[g*3+1], c2 = coords[g*3+2];
  float a2 = np_sq3(c0,c1,c2);
  const float4* pp = pts4 + n*NPTS;
  float bd0=1e30f,bd1=1e30f,bd2=1e30f,bd3=1e30f;
  for (int p = 0; p < NPTS; ++p){
    float4 q = pp[p];
    float d = np_d2(a2, q.w, c0,c1,c2, q.x,q.y,q.z);
    if (d < bd3){
      if (d < bd2){
        bd3=bd2;
        if (d < bd1){ bd2=bd1; if (d < bd0){ bd1=bd0; bd0=d; } else bd1=d; }
        else bd2=d;
      } else bd3=d;
    }
  }
  float w0 = 1.f/bd0, w1 = 1.f/bd1, w2 = 1.f/bd2, w3 = 1.f/bd3;
  #pragma unroll
  for (int off=32; off>0; off>>=1){
    w0 += __shfl_down(w0, off); w1 += __shfl_down(w1, off);
    w2 += __shfl_down(w2, off); w3 += __shfl_down(w3, off);
  }
  int lane = threadIdx.x & 63, wv = threadIdx.x >> 6;
  if (lane == 0){ red[wv][0]=w0; red[wv][1]=w1; red[wv][2]=w2; red[wv][3]=w3; }
  __syncthreads();
  if (threadIdx.x < 4){
    int k = threadIdx.x;
    atomicAdd(&denom[n*4+k], red[0][k]+red[1][k]+red[2][k]+red[3][k]);
  }
}

// ------- fully-unrolled per-thread layer; weights read uniform from global (s_load) -------
// All array indices are compile-time constants => activations stay in VGPRs.
template<int IN, int OUT, bool RELU>
__device__ __forceinline__ void layer_s(const float* in, float* out,
                                        const float* __restrict__ gw,
                                        const float* __restrict__ gb){
  #pragma unroll
  for (int jb = 0; jb < OUT/8; ++jb){
    float a[8];
    #pragma unroll
    for (int j=0;j<8;++j) a[j] = gb[jb*8+j];
    #pragma unroll
    for (int i = 0; i < IN; ++i){
      float x = in[i];
      #pragma unroll
      for (int j=0;j<8;++j) a[j] = fmaf(x, gw[i*OUT + jb*8 + j], a[j]);
    }
    #pragma unroll
    for (int j=0;j<8;++j) out[jb*8+j] = RELU ? fmaxf(a[j],0.f) : a[j];
  }
}

__global__ __launch_bounds__(256, 2) void k_main_r15(
    const float* __restrict__ coords, const float* __restrict__ dirs,
    const float* __restrict__ planes, const float* __restrict__ pemb,
    const float* __restrict__ qw1, const float* __restrict__ qb1,
    const float* __restrict__ qw2, const float* __restrict__ qb2,
    const float* __restrict__ fw1, const float* __restrict__ fb1,
    const float* __restrict__ fw2, const float* __restrict__ fb2,
    const float* __restrict__ fw3, const float* __restrict__ fb3,
    const float* __restrict__ dw,  const float* __restrict__ db,
    const float* __restrict__ rw1, const float* __restrict__ rb1,
    const float* __restrict__ rw2, const float* __restrict__ rb2,
    const float4* __restrict__ pts4, const float* __restrict__ denom,
    float* __restrict__ out)
{
  int tid = threadIdx.x;
  int n = blockIdx.x >> 9;
  int m = ((blockIdx.x & 511) << 8) + tid;
  size_t g = (size_t)n*MQ + m;

  float c0 = coords[g*3+0], c1 = coords[g*3+1], c2 = coords[g*3+2];
  bool sel = (c0 > -1.f) && (c0 < 1.f) && (c1 > -1.f) && (c1 < 1.f) && (c2 > -1.f) && (c2 < 1.f);

  // ---- triplane bilinear sample, mean over planes (r11's proven direct gather) ----
  float feat0[64];
  #pragma unroll
  for (int c=0;c<64;++c) feat0[c]=0.f;
  #pragma unroll
  for (int pl=0; pl<3; ++pl){
    float gx = (pl==2) ? c2 : c0;
    float gy = (pl==1) ? c2 : c1;
    float ix = ((gx + 1.f)*256.f - 1.f)*0.5f;
    float iy = ((gy + 1.f)*256.f - 1.f)*0.5f;
    float x0f = floorf(ix), y0f = floorf(iy);
    int x0 = (int)x0f, y0 = (int)y0f;
    float wxb = ix - x0f, wxa = (x0f + 1.f) - ix;
    float wyb = iy - y0f, wya = (y0f + 1.f) - iy;
    #pragma unroll
    for (int t=0;t<4;++t){
      int xi = x0 + (t & 1);
      int yi = y0 + (t >> 1);
      float wv = ((t&1) ? wxb : wxa) * ((t>>1) ? wyb : wya);
      if (xi>=0 && xi<256 && yi>=0 && yi<256){
        const float* tp_ = planes + (((size_t)(n*3+pl)) << 21) + ((yi<<8)+xi);
        #pragma unroll
        for (int c=0;c<32;++c) feat0[c] = fmaf(wv, tp_[(size_t)c<<16], feat0[c]);
      }
    }
  }
  #pragma unroll
  for (int c=0;c<32;++c) feat0[c] *= (1.f/3.f);

  // ---- kNN: in-kernel scan, bit-identical chain to r11 ----
  float a2 = np_sq3(c0,c1,c2);
  const float4* ppts = pts4 + n*NPTS;
  float bd0=1e30f,bd1=1e30f,bd2=1e30f,bd3=1e30f;
  int   bi0=0,bi1=0,bi2=0,bi3=0;
  for (int p = 0; p < NPTS; ++p){
    float4 q = ppts[p];
    float d = np_d2(a2, q.w, c0,c1,c2, q.x,q.y,q.z);
    if (d < bd3){
      if (d < bd2){
        bd3=bd2; bi3=bi2;
        if (d < bd1){
          bd2=bd1; bi2=bi1;
          if (d < bd0){ bd1=bd0; bi1=bi0; bd0=d; bi0=p; }
          else        { bd1=d;   bi1=p; }
        } else        { bd2=d;   bi2=p; }
      } else          { bd3=d;   bi3=p; }
    }
  }

  // ---- per-neighbor q-MLP (k-loop rolled; no runtime-indexed register arrays) ----
  #pragma unroll 1
  for (int k=0;k<4;++k){
    float dk = (k==0)?bd0:(k==1)?bd1:(k==2)?bd2:bd3;
    int   j  = (k==0)?bi0:(k==1)?bi1:(k==2)?bi2:bi3;
    float wk = (1.f/dk) / denom[n*4+k];
    float hin[59];
    const float4* pe = (const float4*)(pemb + ((size_t)j<<5));
    #pragma unroll
    for (int q4=0;q4<8;++q4){
      float4 v = pe[q4];
      hin[q4*4+0]=v.x; hin[q4*4+1]=v.y; hin[q4*4+2]=v.z; hin[q4*4+3]=v.w;
    }
    float4 pq = ppts[j];
    float vx = c0 - pq.x, vy = c1 - pq.y, vz = c2 - pq.z;
    float nr = fmaxf(sqrtf(vx*vx + vy*vy + vz*vz), 1e-12f);
    float r0 = vx/nr, r1 = vy/nr, r2 = vz/nr;
    #pragma unroll
    for (int d3=0; d3<3; ++d3){
      float rv = (d3==0)?r0:(d3==1)?r1:r2;
      #pragma unroll
      for (int f=0; f<4; ++f){
        float e = rv*(float)(1<<f);
        hin[32 + d3*4 + f] = __sinf(e);
        hin[44 + d3*4 + f] = __cosf(e);
      }
    }
    hin[56]=r0; hin[57]=r1; hin[58]=r2;
    float h1[64]; layer_s<59,64,true >(hin, h1, qw1, qb1);
    float h2[32]; layer_s<64,32,false>(h1, h2, qw2, qb2);
    #pragma unroll
    for (int c=0;c<32;++c) feat0[32+c] = fmaf(wk, h2[c], feat0[32+c]);
  }

  // dist output (bd regs die here)
  float4* odist = (float4*)(out + 262144 + 786432);
  odist[g] = make_float4(bd0,bd1,bd2,bd3);

  // ---- f1 -> f2 fused via 8-wide rank-1 chunks (f1 never fully materialized) ----
  // f1 has 128 channels => 16 chunks of 8.
  // Per-output accumulation order over i is (ib*8+j) ascending 0..127 == r11's order.
  float f2[128];
  #pragma unroll
  for (int o=0;o<128;++o) f2[o] = fb2[o];
  #pragma unroll 1
  for (int ib=0; ib<16; ++ib){
    float t[8];
    #pragma unroll
    for (int j=0;j<8;++j) t[j] = fb1[ib*8+j];
    #pragma unroll
    for (int i=0;i<64;++i){
      float x = feat0[i];
      #pragma unroll
      for (int j=0;j<8;++j) t[j] = fmaf(x, fw1[i*128 + ib*8 + j], t[j]);
    }
    #pragma unroll
    for (int j=0;j<8;++j) t[j] = fmaxf(t[j], 0.f);
    #pragma unroll
    for (int j=0;j<8;++j){
      float x = t[j];
      #pragma unroll
      for (int o=0;o<128;++o) f2[o] = fmaf(x, fw2[(ib*8+j)*128 + o], f2[o]);
    }
  }
  #pragma unroll
  for (int o=0;o<128;++o) f2[o] = fmaxf(f2[o], 0.f);

  // ---- f3 fused with density head and rgb-layer1 (feat slices consumed immediately) ----
  float dacc = db[0];
  float r1v[64];
  #pragma unroll
  for (int o=0;o<64;++o) r1v[o] = rb1[o];
  #pragma unroll 1
  for (int jb=0; jb<16; ++jb){
    float a[8];
    #pragma unroll
    for (int j=0;j<8;++j) a[j] = fb3[jb*8+j];
    #pragma unroll
    for (int i=0;i<128;++i){
      float x = f2[i];
      #pragma unroll
      for (int j=0;j<8;++j) a[j] = fmaf(x, fw3[i*128 + jb*8 + j], a[j]);
    }
    #pragma unroll
    for (int j=0;j<8;++j) dacc = fmaf(a[j], dw[jb*8+j], dacc);
    #pragma unroll
    for (int j=0;j<8;++j){
      float x = a[j];
      #pragma unroll
      for (int o=0;o<64;++o) r1v[o] = fmaf(x, rw1[(jb*8+j)*64 + o], r1v[o]);
    }
  }

  // ---- density head finish ----
  float z  = 10.f*dacc;
  float sp = (z > 0.f) ? (z + log1pf(__expf(-z))) : log1pf(__expf(z));
  float raw = sp*0.1f*(sel ? 1.f : 0.f);
  float dens = 1.f - __expf(-raw);

  // ---- ray harmonics + rgb head (same i-order 0..26 as r11) ----
  float dx = dirs[g*3+0], dy = dirs[g*3+1], dz = dirs[g*3+2];
  float dn = fmaxf(sqrtf(dx*dx+dy*dy+dz*dz), 1e-12f);
  float n0 = dx/dn, n1 = dy/dn, n2 = dz/dn;
  float ext[27];
  #pragma unroll
  for (int d3=0; d3<3; ++d3){
    float nv = (d3==0)?n0:(d3==1)?n1:n2;
    #pragma unroll
    for (int f=0; f<4; ++f){
      float e = nv*(float)(1<<f);
      ext[d3*4 + f]      = __sinf(e);
      ext[12 + d3*4 + f] = __cosf(e);
    }
  }
  ext[24]=n0; ext[25]=n1; ext[26]=n2;
  #pragma unroll
  for (int i=0;i<27;++i){
    float x = ext[i];
    #pragma unroll
    for (int o=0;o<64;++o) r1v[o] = fmaf(x, rw1[(128+i)*64 + o], r1v[o]);
  }
  #pragma unroll
  for (int o=0;o<64;++o) r1v[o] = fmaxf(r1v[o], 0.f);

  float o0 = rb2[0], o1 = rb2[1], o2 = rb2[2];
  #pragma unroll
  for (int i=0;i<64;++i){
    float a = r1v[i];
    o0 = fmaf(a, rw2[i*3+0], o0);
    o1 = fmaf(a, rw2[i*3+1], o1);
    o2 = fmaf(a, rw2[i*3+2], o2);
  }
  o0 = 1.f/(1.f+__expf(-o0))*1.002f - 0.001f;
  o1 = 1.f/(1.f+__expf(-o1))*1.002f - 0.001f;
  o2 = 1.f/(1.f+__expf(-o2))*1.002f - 0.001f;

  // ---- outputs (FLOAT32): [densities NM][rgb 3NM][dist 4NM] ----
  out[g] = dens;
  float* orgb = out + 262144;
  orgb[g*3+0]=o0; orgb[g*3+1]=o1; orgb[g*3+2]=o2;
}

extern "C" void kernel_launch(void* const* d_in, const int* in_sizes, int n_in,
                              void* d_out, int out_size, void* d_ws, size_t ws_size,
                              hipStream_t stream){
  static const int expect[21] = {786432, 786432, 6144, 12582912, 32768,
                                 3776, 64, 2048, 32, 8192, 128, 16384, 128, 16384, 128,
                                 128, 1, 9920, 64, 192, 3};
  if (n_in != 21){ k_err_r15<<<1,1,0,stream>>>(128.f, (float*)d_out); return; }
  if (out_size != 2097152){ k_err_r15<<<1,1,0,stream>>>(129.f, (float*)d_out); return; }
  for (int i = 0; i < 21; ++i){
    if (in_sizes[i] != expect[i]){
      k_err_r15<<<1,1,0,stream>>>(130.f + (float)i, (float*)d_out);
      return;
    }
  }

  const float* coords = (const float*)d_in[0];
  const float* dirs   = (const float*)d_in[1];
  const float* pts    = (const float*)d_in[2];
  const float* planes = (const float*)d_in[3];
  const float* pemb   = (const float*)d_in[4];
  const float* qw1 = (const float*)d_in[5];  const float* qb1 = (const float*)d_in[6];
  const float* qw2 = (const float*)d_in[7];  const float* qb2 = (const float*)d_in[8];
  const float* fw1 = (const float*)d_in[9];  const float* fb1 = (const float*)d_in[10];
  const float* fw2 = (const float*)d_in[11]; const float* fb2 = (const float*)d_in[12];
  const float* fw3 = (const float*)d_in[13]; const float* fb3 = (const float*)d_in[14];
  const float* dw  = (const float*)d_in[15]; const float* db  = (const float*)d_in[16];
  const float* rw1 = (const float*)d_in[17]; const float* rb1 = (const float*)d_in[18];
  const float* rw2 = (const float*)d_in[19]; const float* rb2 = (const float*)d_in[20];

  char* ws = (char*)d_ws;
  float*  denom = (float*)ws;                 // 8 floats @ 0
  float4* pts4  = (float4*)(ws + WS_PTS4);    // 2*1024*16 B

  // Unconditional launch sequence — identical structure every call.
  k_prep_r15 <<<8, 256, 0, stream>>>(pts, pts4, denom);
  k_denom_r15<<<dim3(512,2), 256, 0, stream>>>(coords, pts4, denom);
  k_main_r15 <<<1024, 256, 0, stream>>>(coords, dirs, planes, pemb,
      qw1, qb1, qw2, qb2, fw1, fb1, fw2, fb2, fw3, fb3, dw, db, rw1, rb1, rw2, rb2,
      pts4, denom, (float*)d_out);
}